// Round 16
// baseline (183.158 us; speedup 1.0000x reference)
//
#include <hip/hip_runtime.h>
#include <cstdint>
#include <cstddef>

#define NB 2048
#define NT 512
#define ND 64
#define NR 50
#define NE 4             // batch elements per block
#define REVP 68          // review row stride (floats)
#define AQ 12800         // A-quarter LDS bytes per elem: 50 rows x 256B
#define BQ 16384         // B-quarter LDS bytes

typedef __attribute__((ext_vector_type(8))) short bf16x8;
typedef __attribute__((ext_vector_type(4))) float f32x4;

__device__ inline unsigned short f2bf_rne(float x) {
    unsigned int u = __float_as_uint(x);
    u += 0x7fffu + ((u >> 16) & 1u);
    return (unsigned short)(u >> 16);
}

__device__ inline bf16x8 cvt8_rne(float4 v0, float4 v1) {
    union { unsigned int u[4]; bf16x8 v; } P;
    asm("v_cvt_pk_bf16_f32 %0, %1, %2" : "=v"(P.u[0]) : "v"(v0.x), "v"(v0.y));
    asm("v_cvt_pk_bf16_f32 %0, %1, %2" : "=v"(P.u[1]) : "v"(v0.z), "v"(v0.w));
    asm("v_cvt_pk_bf16_f32 %0, %1, %2" : "=v"(P.u[2]) : "v"(v1.x), "v"(v1.y));
    asm("v_cvt_pk_bf16_f32 %0, %1, %2" : "=v"(P.u[3]) : "v"(v1.z), "v"(v1.w));
    return P.v;
}

__device__ inline void gload16(const void* gsrc, void* ldst) {
    __builtin_amdgcn_global_load_lds(
        (const __attribute__((address_space(1))) unsigned int*)gsrc,
        (__attribute__((address_space(3))) unsigned int*)ldst, 16, 0, 0);
}

// ---------------------------------------------------------------------------
__global__ __launch_bounds__(256) void prep_kernel(
    const float* __restrict__ tw,
    const float* __restrict__ fc_u_w, const float* __restrict__ fc_ru_w,
    const float* __restrict__ fc_i_w, const float* __restrict__ fc_ri_w,
    unsigned short* __restrict__ bhi,
    unsigned short* __restrict__ fuhi, unsigned short* __restrict__ fihi)
{
    int i = blockIdx.x * 256 + threadIdx.x;          // 192*256 = 49152
    if (i < 32768) {
        int j  = i & 7;
        int l  = (i >> 3) & 63;
        int n  = (i >> 9) & 3;
        int kk = i >> 11;                            // 0..15
        int t = kk * 32 + ((l >> 4) << 3) + j;
        int d = n * 16 + (l & 15);
        bhi[i] = f2bf_rne(tw[t * ND + d]);
    } else {
        int q = i - 32768;                           // 0..16383
        int br = q >> 13;                            // 0 user, 1 item
        int e = q & 8191;
        int j  = e & 7;
        int l  = (e >> 3) & 63;
        int n  = (e >> 9) & 3;
        int kk = e >> 11;                            // 0..3
        int k = kk * 32 + ((l >> 4) << 3) + j;       // 0..127
        int col = n * 16 + (l & 15);
        const float* W = (k < 64) ? (br ? fc_ri_w : fc_ru_w)
                                  : (br ? fc_i_w  : fc_u_w);
        unsigned short hi = f2bf_rne(W[(k & 63) * ND + col]);
        if (br) fihi[e] = hi; else fuhi[e] = hi;
    }
}

// ---------------------------------------------------------------------------
__global__ __launch_bounds__(256) void colsum_kernel(const float* __restrict__ tw,
                                                     float* __restrict__ colsum) {
    __shared__ float part[4][ND];
    int d = threadIdx.x & 63, p = threadIdx.x >> 6;
    float s = 0.f;
    for (int t = p; t < NT; t += 4) s += tw[t * ND + d];
    part[p][d] = s;
    __syncthreads();
    if (threadIdx.x < ND)
        colsum[d] = part[0][d] + part[1][d] + part[2][d] + part[3][d];
}

// pinned issue: elem e, row-slot i (512B contiguous per wave instruction)
#define AISSUE(e, i)                                                           \
    int r##e##_##i = (i) * 4 + wave;                                           \
    r##e##_##i = r##e##_##i > NR - 1 ? NR - 1 : r##e##_##i;                    \
    float2 dA##e##_##i;                                                        \
    {                                                                          \
        const float* _p = arowp[e] + (size_t)r##e##_##i * NT + q * 128 + lane * 2; \
        asm volatile("global_load_dwordx2 %0, %1, off"                         \
                     : "=v"(dA##e##_##i) : "v"(_p) : "memory");                \
    }
#define AROW(e)                                                                \
    AISSUE(e, 0) AISSUE(e, 1) AISSUE(e, 2) AISSUE(e, 3) AISSUE(e, 4)           \
    AISSUE(e, 5) AISSUE(e, 6) AISSUE(e, 7) AISSUE(e, 8) AISSUE(e, 9)           \
    AISSUE(e, 10) AISSUE(e, 11) AISSUE(e, 12)

// retire+convert; W carries the group-leader literal vmcnt (volatile asm are
// strictly program-ordered, so followers inherit the leader's wait)
#define ACON(e, i, W)                                                          \
    {                                                                          \
        unsigned int _o;                                                       \
        asm volatile(W "v_cvt_pk_bf16_f32 %0, %1, %2"                          \
                     : "=v"(_o)                                                \
                     : "v"(dA##e##_##i.x), "v"(dA##e##_##i.y) : "memory");     \
        *reinterpret_cast<unsigned int*>(arena + (e) * AQ +                    \
            r##e##_##i * 256 +                                                 \
            ((((lane >> 2) ^ (r##e##_##i & 15)) << 4) | ((lane & 3) << 2))) = _o; \
    }
#define ACROW(e, W)                                                            \
    ACON(e, 0, W) ACON(e, 1, "") ACON(e, 2, "") ACON(e, 3, "") ACON(e, 4, "")  \
    ACON(e, 5, "") ACON(e, 6, "") ACON(e, 7, "") ACON(e, 8, "") ACON(e, 9, "") \
    ACON(e, 10, "") ACON(e, 11, "") ACON(e, 12, "")

// ---------------------------------------------------------------------------
// Block = 4 waves x 4 batch elements (grid 1024), 2 blocks/CU.
// Per K-quarter (128 cols): stage B-quarter (16KB gload_lds, reused by 4
// elems) + 52 pinned A loads (all in flight), group-retired at literal
// vmcnt(39/26/13/0); swizzled bf16 ds_write; then pure-LDS MFMA (B-frag
// reuse x4). B/fc global traffic amortized 4x vs round-15.
__global__ __launch_bounds__(256, 2) void branch_kernel(
    const int* __restrict__ user, const int* __restrict__ item,
    const float* __restrict__ user_r_topic, const float* __restrict__ item_r_topic,
    const float* __restrict__ user_embed_w, const float* __restrict__ item_embed_w,
    const float* __restrict__ user_att_w, const float* __restrict__ item_att_w,
    const unsigned short* __restrict__ bhi,
    const unsigned short* __restrict__ fuhi, const unsigned short* __restrict__ fihi,
    const float* __restrict__ fc_u_b, const float* __restrict__ fc_ru_b,
    const float* __restrict__ fc_i_b, const float* __restrict__ fc_ri_b,
    const float* __restrict__ h_u_w, const float* __restrict__ h_u_b,
    const float* __restrict__ h_i_w, const float* __restrict__ h_i_b,
    const float* __restrict__ colsum,
    float* __restrict__ u_vec, float* __restrict__ i_vec)
{
    // arena: A quarters [e][50][256B] at [0, 51200) | B-quarter [51200, 67584)
    // rev[4][50][68] f32 (54.4 KB) overlays arena after the K-loop.
    __shared__ __align__(16) unsigned char arena[NE * AQ + BQ];
    __shared__ float lds_logit[NE][NR + 2];

    const int tid = threadIdx.x, wave = tid >> 6, lane = tid & 63;
    const int g = lane >> 4, c16 = lane & 15;

    const int E0 = blockIdx.x * NE;         // 4 consecutive elems, same branch
    const int branch = E0 >> 11;            // 0 = user, 1 = item

    const int*   ids     = branch ? item           : user;
    const float* r_topic = branch ? item_r_topic   : user_r_topic;
    const float* emb_w   = branch ? item_embed_w   : user_embed_w;
    const float* att_w   = branch ? item_att_w     : user_att_w;
    const unsigned short* fhi = branch ? fihi : fuhi;
    const float* fc_a_b  = branch ? fc_i_b         : fc_u_b;
    const float* fc_r_b  = branch ? fc_ri_b        : fc_ru_b;
    const float* h_w     = branch ? h_i_w          : h_u_w;
    const float* h_b     = branch ? h_i_b          : h_u_b;
    float*       out_vec = branch ? i_vec          : u_vec;

    const int rowg = wave * 16 + c16;
    const int rowc = rowg < NR ? rowg : NR - 1;
    unsigned char* blds = arena + NE * AQ;

    int bidx[NE], idv[NE];
    const float* arowp[NE];
#pragma unroll
    for (int e = 0; e < NE; ++e) {
        bidx[e] = (E0 + e) & (NB - 1);
        idv[e]  = ids[bidx[e]];
        arowp[e] = r_topic + (size_t)bidx[e] * NR * NT;
    }

    f32x4 acc[NE][4];
#pragma unroll
    for (int e = 0; e < NE; ++e)
#pragma unroll
        for (int n = 0; n < 4; ++n) acc[e][n] = (f32x4){0.f, 0.f, 0.f, 0.f};

    for (int q = 0; q < 4; ++q) {
        // ---- B-quarter: 4 async gload_lds per thread (16 KB block-wide) ----
        {
            const unsigned char* srcB = (const unsigned char*)bhi + (size_t)q * BQ;
#pragma unroll
            for (int i = 0; i < 4; ++i) {
                size_t off = (size_t)(i * 256 + tid) * 16;
                gload16(srcB + off, blds + off);
            }
        }
        __builtin_amdgcn_sched_barrier(0);
        // ---- 52 pinned A loads, all in flight (queue: 4 B + 52 A) ----
        AROW(0) AROW(1) AROW(2) AROW(3)
        // ---- group retirement: leader wait + ordered cvt/ds_write ----
        ACROW(0, "s_waitcnt vmcnt(39)\n\t")
        ACROW(1, "s_waitcnt vmcnt(26)\n\t")
        ACROW(2, "s_waitcnt vmcnt(13)\n\t")
        ACROW(3, "s_waitcnt vmcnt(0)\n\t")
        __syncthreads();                 // A+B quarter resident

        // ---- compute: 4 ksteps, B-frag reuse x4 elems ----
#pragma unroll
        for (int kkl = 0; kkl < 4; ++kkl) {
            bf16x8 af[NE];
#pragma unroll
            for (int e = 0; e < NE; ++e)
                af[e] = *reinterpret_cast<const bf16x8*>(
                    arena + e * AQ + rowc * 256 + (((kkl * 4 + g) ^ (rowc & 15)) << 4));
#pragma unroll
            for (int n = 0; n < 4; ++n) {
                bf16x8 bh = *reinterpret_cast<const bf16x8*>(
                    blds + (size_t)((kkl * 4 + n) * 64 + lane) * 16);
#pragma unroll
                for (int e = 0; e < NE; ++e)
                    acc[e][n] = __builtin_amdgcn_mfma_f32_16x16x32_bf16(af[e], bh, acc[e][n], 0, 0, 0);
            }
        }
        __syncthreads();                 // all LDS reads done before restage
    }

    // rev overlay on arena
    float (*rev)[NR][REVP] = reinterpret_cast<float(*)[NR][REVP]>(arena);
#pragma unroll
    for (int e = 0; e < NE; ++e)
#pragma unroll
        for (int n = 0; n < 4; ++n)
#pragma unroll
            for (int r4 = 0; r4 < 4; ++r4) {
                int r = wave * 16 + g * 4 + r4;
                if (r < NR) rev[e][r][n * 16 + c16] = acc[e][n][r4];
            }
    // no barrier: epilogue reads only this wave's own rows

    // ---- epilogue s-matmul: s[e][50x64] = review@fcR + att@fcA (K=128) ----
    f32x4 s4[NE][4];
#pragma unroll
    for (int e = 0; e < NE; ++e)
#pragma unroll
        for (int n = 0; n < 4; ++n) s4[e][n] = (f32x4){0.f, 0.f, 0.f, 0.f};

#pragma unroll
    for (int kk2 = 0; kk2 < 4; ++kk2) {
        bf16x8 bh[4];
#pragma unroll
        for (int n = 0; n < 4; ++n)
            bh[n] = *(reinterpret_cast<const bf16x8*>(fhi + (size_t)(kk2 * 4 + n) * 512) + lane);
#pragma unroll
        for (int e = 0; e < NE; ++e) {
            bf16x8 ah;
            if (kk2 < 2) {
                const float* rp = &rev[e][rowc][kk2 * 32 + g * 8];
                ah = cvt8_rne(*reinterpret_cast<const float4*>(rp),
                              *reinterpret_cast<const float4*>(rp + 4));
            } else {
                const float* ap = att_w + (size_t)idv[e] * ND + (kk2 - 2) * 32 + g * 8;
                ah = cvt8_rne(*reinterpret_cast<const float4*>(ap),
                              *reinterpret_cast<const float4*>(ap + 4));
            }
#pragma unroll
            for (int n = 0; n < 4; ++n)
                s4[e][n] = __builtin_amdgcn_mfma_f32_16x16x32_bf16(ah, bh[n], s4[e][n], 0, 0, 0);
        }
    }

    // bias + relu + dot with h_w, 16-lane reduce -> logits (per element)
    const float hb = h_b[0];
#pragma unroll
    for (int e = 0; e < NE; ++e) {
        float p0 = 0.f, p1 = 0.f, p2 = 0.f, p3 = 0.f;
#pragma unroll
        for (int n = 0; n < 4; ++n) {
            float hwn = h_w[n * 16 + c16];
            float bs = fc_r_b[n * 16 + c16] + fc_a_b[n * 16 + c16];
            p0 = fmaf(fmaxf(s4[e][n][0] + bs, 0.f), hwn, p0);
            p1 = fmaf(fmaxf(s4[e][n][1] + bs, 0.f), hwn, p1);
            p2 = fmaf(fmaxf(s4[e][n][2] + bs, 0.f), hwn, p2);
            p3 = fmaf(fmaxf(s4[e][n][3] + bs, 0.f), hwn, p3);
        }
#pragma unroll
        for (int off = 1; off < 16; off <<= 1) {
            p0 += __shfl_xor(p0, off);
            p1 += __shfl_xor(p1, off);
            p2 += __shfl_xor(p2, off);
            p3 += __shfl_xor(p3, off);
        }
        if (c16 == 0) {
            int rb = wave * 16 + g * 4;
            if (rb + 0 < NR) lds_logit[e][rb + 0] = p0 + hb;
            if (rb + 1 < NR) lds_logit[e][rb + 1] = p1 + hb;
            if (rb + 2 < NR) lds_logit[e][rb + 2] = p2 + hb;
            if (rb + 3 < NR) lds_logit[e][rb + 3] = p3 + hb;
        }
    }
    __syncthreads();   // publish rev rows + logits

    // softmax + pooling + colsum scale + emb add (wave e -> elem e)
    {
        const int e = wave;
        const int b = bidx[e];
        const int id = idv[e];
        float m = -1e30f;
        for (int r = 0; r < NR; ++r) m = fmaxf(m, lds_logit[e][r]);
        float sum = 0.f;
        for (int r = 0; r < NR; ++r) sum += __expf(lds_logit[e][r] - m);
        float inv = 1.f / sum;
        float feat = 0.f;
        for (int r = 0; r < NR; ++r)
            feat = fmaf(__expf(lds_logit[e][r] - m), rev[e][r][lane], feat);
        feat *= inv;
        out_vec[(size_t)b * ND + lane] = feat * colsum[lane] + emb_w[(size_t)id * ND + lane];
    }
}

// ---------------------------------------------------------------------------
__global__ __launch_bounds__(64) void final_kernel(
    const float* __restrict__ u_vec, const float* __restrict__ i_vec,
    const float* __restrict__ fc_pre_w, const float* __restrict__ fc_pre_b,
    float* __restrict__ out)
{
    int b = blockIdx.x, lane = threadIdx.x;
    float v = u_vec[(size_t)b * ND + lane] * fc_pre_w[lane]
            + i_vec[(size_t)b * ND + lane] * fc_pre_w[ND + lane];
#pragma unroll
    for (int off = 32; off; off >>= 1) v += __shfl_xor(v, off);
    if (lane == 0) out[b] = fmaxf(v + fc_pre_b[0], 0.f);
}

// ---------------------------------------------------------------------------
extern "C" void kernel_launch(void* const* d_in, const int* in_sizes, int n_in,
                              void* d_out, int out_size, void* d_ws, size_t ws_size,
                              hipStream_t stream) {
    (void)in_sizes; (void)n_in; (void)out_size; (void)ws_size;

    const int*   user         = (const int*)d_in[0];
    const int*   item         = (const int*)d_in[1];
    const float* user_r_topic = (const float*)d_in[2];
    const float* item_r_topic = (const float*)d_in[3];
    const float* user_embed_w = (const float*)d_in[4];
    const float* item_embed_w = (const float*)d_in[5];
    const float* user_att_w   = (const float*)d_in[6];
    const float* item_att_w   = (const float*)d_in[7];
    const float* topic_w      = (const float*)d_in[8];
    const float* fc_u_w       = (const float*)d_in[9];
    const float* fc_u_b       = (const float*)d_in[10];
    const float* fc_ru_w      = (const float*)d_in[11];
    const float* fc_ru_b      = (const float*)d_in[12];
    const float* fc_i_w       = (const float*)d_in[13];
    const float* fc_i_b       = (const float*)d_in[14];
    const float* fc_ri_w      = (const float*)d_in[15];
    const float* fc_ri_b      = (const float*)d_in[16];
    const float* h_u_w        = (const float*)d_in[17];
    const float* h_u_b        = (const float*)d_in[18];
    const float* h_i_w        = (const float*)d_in[19];
    const float* h_i_b        = (const float*)d_in[20];
    const float* fc_pre_w     = (const float*)d_in[21];
    const float* fc_pre_b     = (const float*)d_in[22];

    // workspace layout
    unsigned short* bhi  = (unsigned short*)d_ws;      // 32768
    unsigned short* fuhi = bhi + 32768;                // 8192
    unsigned short* fihi = fuhi + 8192;                // 8192
    float* colsum = (float*)(fihi + 8192);             // 64
    float* u_vec  = colsum + 64;                       // NB*ND
    float* i_vec  = u_vec + NB * ND;                   // NB*ND

    prep_kernel<<<192, 256, 0, stream>>>(topic_w, fc_u_w, fc_ru_w, fc_i_w, fc_ri_w,
                                         bhi, fuhi, fihi);
    colsum_kernel<<<1, 256, 0, stream>>>(topic_w, colsum);

    branch_kernel<<<(2 * NB) / NE, 256, 0, stream>>>(
        user, item, user_r_topic, item_r_topic,
        user_embed_w, item_embed_w, user_att_w, item_att_w,
        bhi, fuhi, fihi,
        fc_u_b, fc_ru_b, fc_i_b, fc_ri_b,
        h_u_w, h_u_b, h_i_w, h_i_b,
        colsum, u_vec, i_vec);

    final_kernel<<<NB, 64, 0, stream>>>(u_vec, i_vec, fc_pre_w, fc_pre_b,
                                        (float*)d_out);
}

// Round 17
// 132.904 us; speedup vs baseline: 1.3781x; 1.3781x over previous
//
#include <hip/hip_runtime.h>
#include <cstdint>
#include <cstddef>

#define NB 2048
#define NT 512
#define ND 64
#define NR 50
#define REVP 68          // review row stride (floats)
#define ALDS 25600       // A-half LDS bytes: 50 rows x 512B (256 bf16)

typedef __attribute__((ext_vector_type(8))) short bf16x8;
typedef __attribute__((ext_vector_type(4))) float f32x4;

__device__ inline unsigned short f2bf_rne(float x) {
    unsigned int u = __float_as_uint(x);
    u += 0x7fffu + ((u >> 16) & 1u);
    return (unsigned short)(u >> 16);
}

__device__ inline bf16x8 cvt8_rne(float4 v0, float4 v1) {
    union { unsigned int u[4]; bf16x8 v; } P;
    asm("v_cvt_pk_bf16_f32 %0, %1, %2" : "=v"(P.u[0]) : "v"(v0.x), "v"(v0.y));
    asm("v_cvt_pk_bf16_f32 %0, %1, %2" : "=v"(P.u[1]) : "v"(v0.z), "v"(v0.w));
    asm("v_cvt_pk_bf16_f32 %0, %1, %2" : "=v"(P.u[2]) : "v"(v1.x), "v"(v1.y));
    asm("v_cvt_pk_bf16_f32 %0, %1, %2" : "=v"(P.u[3]) : "v"(v1.z), "v"(v1.w));
    return P.v;
}

__device__ inline void gload16(const void* gsrc, void* ldst) {
    __builtin_amdgcn_global_load_lds(
        (const __attribute__((address_space(1))) unsigned int*)gsrc,
        (__attribute__((address_space(3))) unsigned int*)ldst, 16, 0, 0);
}

// ---------------------------------------------------------------------------
__global__ __launch_bounds__(256) void prep_kernel(
    const float* __restrict__ tw,
    const float* __restrict__ fc_u_w, const float* __restrict__ fc_ru_w,
    const float* __restrict__ fc_i_w, const float* __restrict__ fc_ri_w,
    unsigned short* __restrict__ bhi,
    unsigned short* __restrict__ fuhi, unsigned short* __restrict__ fihi)
{
    int i = blockIdx.x * 256 + threadIdx.x;          // 192*256 = 49152
    if (i < 32768) {
        int j  = i & 7;
        int l  = (i >> 3) & 63;
        int n  = (i >> 9) & 3;
        int kk = i >> 11;                            // 0..15
        int t = kk * 32 + ((l >> 4) << 3) + j;
        int d = n * 16 + (l & 15);
        bhi[i] = f2bf_rne(tw[t * ND + d]);
    } else {
        int q = i - 32768;                           // 0..16383
        int br = q >> 13;                            // 0 user, 1 item
        int e = q & 8191;
        int j  = e & 7;
        int l  = (e >> 3) & 63;
        int n  = (e >> 9) & 3;
        int kk = e >> 11;                            // 0..3
        int k = kk * 32 + ((l >> 4) << 3) + j;       // 0..127
        int col = n * 16 + (l & 15);
        const float* W = (k < 64) ? (br ? fc_ri_w : fc_ru_w)
                                  : (br ? fc_i_w  : fc_u_w);
        unsigned short hi = f2bf_rne(W[(k & 63) * ND + col]);
        if (br) fihi[e] = hi; else fuhi[e] = hi;
    }
}

// ---------------------------------------------------------------------------
__global__ __launch_bounds__(256) void colsum_kernel(const float* __restrict__ tw,
                                                     float* __restrict__ colsum) {
    __shared__ float part[4][ND];
    int d = threadIdx.x & 63, p = threadIdx.x >> 6;
    float s = 0.f;
    for (int t = p; t < NT; t += 4) s += tw[t * ND + d];
    part[p][d] = s;
    __syncthreads();
    if (threadIdx.x < ND)
        colsum[d] = part[0][d] + part[1][d] + part[2][d] + part[3][d];
}

// pinned issue of one A row-segment (1KB contiguous per wave instruction)
#define AISSUE(P, i, hh)                                                       \
    int r_##P##_##i = (i) * 4 + wave;                                          \
    r_##P##_##i = r_##P##_##i > NR - 1 ? NR - 1 : r_##P##_##i;                 \
    float4 dA_##P##_##i;                                                       \
    {                                                                          \
        const float* _p = Abase + (size_t)r_##P##_##i * NT + (hh) * 256 + lane * 4; \
        asm volatile("global_load_dwordx4 %0, %1, off"                         \
                     : "=v"(dA_##P##_##i) : "v"(_p) : "memory");               \
    }
#define AROW(P, hh)                                                            \
    AISSUE(P, 0, hh)  AISSUE(P, 1, hh)  AISSUE(P, 2, hh)  AISSUE(P, 3, hh)     \
    AISSUE(P, 4, hh)  AISSUE(P, 5, hh)  AISSUE(P, 6, hh)  AISSUE(P, 7, hh)     \
    AISSUE(P, 8, hh)  AISSUE(P, 9, hh)  AISSUE(P, 10, hh) AISSUE(P, 11, hh)    \
    AISSUE(P, 12, hh)

// interlocked retire+convert: wait and use fused in ONE asm block
#define ACONSUME(P, i, N)                                                      \
    {                                                                          \
        unsigned int _o0, _o1;                                                 \
        asm volatile("s_waitcnt vmcnt(" #N ")\n\t"                             \
                     "v_cvt_pk_bf16_f32 %0, %2, %3\n\t"                        \
                     "v_cvt_pk_bf16_f32 %1, %4, %5"                            \
                     : "=&v"(_o0), "=&v"(_o1)                                  \
                     : "v"(dA_##P##_##i.x), "v"(dA_##P##_##i.y),               \
                       "v"(dA_##P##_##i.z), "v"(dA_##P##_##i.w)                \
                     : "memory");                                              \
        uint2 _w; _w.x = _o0; _w.y = _o1;                                      \
        *reinterpret_cast<uint2*>(arena + r_##P##_##i * 512 +                  \
            ((lane ^ ((r_##P##_##i & 7) << 1)) * 8)) = _w;                     \
    }
#define ACROW(P)                                                               \
    ACONSUME(P, 0, 12) ACONSUME(P, 1, 11) ACONSUME(P, 2, 10) ACONSUME(P, 3, 9) \
    ACONSUME(P, 4, 8)  ACONSUME(P, 5, 7)  ACONSUME(P, 6, 6)  ACONSUME(P, 7, 5) \
    ACONSUME(P, 8, 4)  ACONSUME(P, 9, 3)  ACONSUME(P, 10, 2) ACONSUME(P, 11, 1)\
    ACONSUME(P, 12, 0)

// ---------------------------------------------------------------------------
// One block per (branch, batch element), 4 waves, 2 blocks/CU.
// r15 structure + SOFTWARE PIPELINE: half1's 13 pinned A loads are issued
// BEFORE half0's compute and stay in flight (52 VGPR live) across it --
// memory requests outstanding during the LDS compute phase.
__global__ __launch_bounds__(256, 2) void branch_kernel(
    const int* __restrict__ user, const int* __restrict__ item,
    const float* __restrict__ user_r_topic, const float* __restrict__ item_r_topic,
    const float* __restrict__ user_embed_w, const float* __restrict__ item_embed_w,
    const float* __restrict__ user_att_w, const float* __restrict__ item_att_w,
    const unsigned short* __restrict__ bhi,
    const unsigned short* __restrict__ fuhi, const unsigned short* __restrict__ fihi,
    const float* __restrict__ fc_u_b, const float* __restrict__ fc_ru_b,
    const float* __restrict__ fc_i_b, const float* __restrict__ fc_ri_b,
    const float* __restrict__ h_u_w, const float* __restrict__ h_u_b,
    const float* __restrict__ h_i_w, const float* __restrict__ h_i_b,
    const float* __restrict__ colsum,
    float* __restrict__ u_vec, float* __restrict__ i_vec)
{
    __shared__ __align__(16) unsigned char arena[ALDS + 32768];
    __shared__ float lds_logit[NR + 2];

    const int tid = threadIdx.x, wave = tid >> 6, lane = tid & 63;
    const int g = lane >> 4, c16 = lane & 15;

    const int bb = blockIdx.x;
    const int branch = bb >> 11;          // 0 = user, 1 = item
    const int b = bb & (NB - 1);

    const int*   ids     = branch ? item           : user;
    const float* r_topic = branch ? item_r_topic   : user_r_topic;
    const float* emb_w   = branch ? item_embed_w   : user_embed_w;
    const float* att_w   = branch ? item_att_w     : user_att_w;
    const unsigned short* fhi = branch ? fihi : fuhi;
    const float* fc_a_b  = branch ? fc_i_b         : fc_u_b;
    const float* fc_r_b  = branch ? fc_ri_b        : fc_ru_b;
    const float* h_w     = branch ? h_i_w          : h_u_w;
    const float* h_b     = branch ? h_i_b          : h_u_b;
    float*       out_vec = branch ? i_vec          : u_vec;

    const int id = ids[b];
    const int rowg = wave * 16 + c16;
    const int rowc = rowg < NR ? rowg : NR - 1;
    unsigned char* blds = arena + ALDS;

    const float* Abase = r_topic + (size_t)b * NR * NT;

    f32x4 acc[4];
#pragma unroll
    for (int n = 0; n < 4; ++n) acc[n] = (f32x4){0.f, 0.f, 0.f, 0.f};

    auto kstep = [&](int kkl) {
        bf16x8 af = *reinterpret_cast<const bf16x8*>(
            arena + rowc * 512 + (((kkl * 4 + g) ^ (rowc & 7)) << 4));
#pragma unroll
        for (int n = 0; n < 4; ++n) {
            bf16x8 bh = *reinterpret_cast<const bf16x8*>(
                blds + (size_t)((kkl * 4 + n) * 64 + lane) * 16);
            acc[n] = __builtin_amdgcn_mfma_f32_16x16x32_bf16(af, bh, acc[n], 0, 0, 0);
        }
    };
    auto stageB = [&](int h) {
        const unsigned char* src = (const unsigned char*)bhi + (size_t)h * 32768;
#pragma unroll
        for (int i = 0; i < 8; ++i) {
            size_t off = (size_t)(i * 256 + tid) * 16;
            gload16(src + off, blds + off);
        }
    };

    // ---- prologue: B half0 + pinned A half0, retire, barrier ----
    stageB(0);
    AROW(a, 0)
    ACROW(a)          // vmcnt(12..0): retires A and (by order) all B half0
    __syncthreads();  // half0 A+B resident

    // ---- PIPELINE: issue half1's A loads BEFORE half0 compute ----
    AROW(p, 1)        // 13 loads in flight across the whole compute phase

#pragma unroll
    for (int kkl = 0; kkl < 8; ++kkl) kstep(kkl);
    __syncthreads();  // all waves done reading half0 A/B LDS

    ACROW(p)          // retire half1 A (latency already covered by compute)
    stageB(1);
    asm volatile("s_waitcnt vmcnt(0)" ::: "memory");
    __builtin_amdgcn_sched_barrier(0);
    __syncthreads();  // half1 A+B resident

#pragma unroll
    for (int kkl = 0; kkl < 8; ++kkl) kstep(kkl);

    __syncthreads();  // all LDS reads done -> overlay rev
    float (*rev)[REVP] = reinterpret_cast<float(*)[REVP]>(blds);
#pragma unroll
    for (int n = 0; n < 4; ++n)
#pragma unroll
        for (int r4 = 0; r4 < 4; ++r4) {
            int r = wave * 16 + g * 4 + r4;
            if (r < NR) rev[r][n * 16 + c16] = acc[n][r4];
        }
    // no barrier: epilogue reads only this wave's own rows

    // ---- epilogue s-matmul: s[50x64] = review@fcR + att@fcA (K=128, bf16) ----
    f32x4 s4[4];
#pragma unroll
    for (int n = 0; n < 4; ++n) s4[n] = (f32x4){0.f, 0.f, 0.f, 0.f};

#pragma unroll
    for (int kk2 = 0; kk2 < 4; ++kk2) {
        bf16x8 bh[4];
#pragma unroll
        for (int n = 0; n < 4; ++n)
            bh[n] = *(reinterpret_cast<const bf16x8*>(fhi + (size_t)(kk2 * 4 + n) * 512) + lane);
        bf16x8 ah;
        if (kk2 < 2) {
            const float* rp = &rev[rowc][kk2 * 32 + g * 8];
            ah = cvt8_rne(*reinterpret_cast<const float4*>(rp),
                          *reinterpret_cast<const float4*>(rp + 4));
        } else {
            const float* ap = att_w + (size_t)id * ND + (kk2 - 2) * 32 + g * 8;
            ah = cvt8_rne(*reinterpret_cast<const float4*>(ap),
                          *reinterpret_cast<const float4*>(ap + 4));
        }
#pragma unroll
        for (int n = 0; n < 4; ++n)
            s4[n] = __builtin_amdgcn_mfma_f32_16x16x32_bf16(ah, bh[n], s4[n], 0, 0, 0);
    }

    // bias + relu + dot with h_w, then 16-lane reduce -> logits
    const float hb = h_b[0];
    float p0 = 0.f, p1 = 0.f, p2 = 0.f, p3 = 0.f;
#pragma unroll
    for (int n = 0; n < 4; ++n) {
        float hwn = h_w[n * 16 + c16];
        float bs = fc_r_b[n * 16 + c16] + fc_a_b[n * 16 + c16];
        p0 = fmaf(fmaxf(s4[n][0] + bs, 0.f), hwn, p0);
        p1 = fmaf(fmaxf(s4[n][1] + bs, 0.f), hwn, p1);
        p2 = fmaf(fmaxf(s4[n][2] + bs, 0.f), hwn, p2);
        p3 = fmaf(fmaxf(s4[n][3] + bs, 0.f), hwn, p3);
    }
#pragma unroll
    for (int off = 1; off < 16; off <<= 1) {
        p0 += __shfl_xor(p0, off);
        p1 += __shfl_xor(p1, off);
        p2 += __shfl_xor(p2, off);
        p3 += __shfl_xor(p3, off);
    }
    if (c16 == 0) {
        int rb = wave * 16 + g * 4;
        if (rb + 0 < NR) lds_logit[rb + 0] = p0 + hb;
        if (rb + 1 < NR) lds_logit[rb + 1] = p1 + hb;
        if (rb + 2 < NR) lds_logit[rb + 2] = p2 + hb;
        if (rb + 3 < NR) lds_logit[rb + 3] = p3 + hb;
    }
    __syncthreads();   // publish rev rows + logits to wave 0

    // softmax + pooling + colsum scale + emb add (wave 0)
    if (wave == 0) {
        float m = -1e30f;
        for (int r = 0; r < NR; ++r) m = fmaxf(m, lds_logit[r]);
        float sum = 0.f;
        for (int r = 0; r < NR; ++r) sum += __expf(lds_logit[r] - m);
        float inv = 1.f / sum;
        float feat = 0.f;
        for (int r = 0; r < NR; ++r)
            feat = fmaf(__expf(lds_logit[r] - m), rev[r][lane], feat);
        feat *= inv;
        out_vec[(size_t)b * ND + lane] = feat * colsum[lane] + emb_w[(size_t)id * ND + lane];
    }
}

// ---------------------------------------------------------------------------
__global__ __launch_bounds__(64) void final_kernel(
    const float* __restrict__ u_vec, const float* __restrict__ i_vec,
    const float* __restrict__ fc_pre_w, const float* __restrict__ fc_pre_b,
    float* __restrict__ out)
{
    int b = blockIdx.x, lane = threadIdx.x;
    float v = u_vec[(size_t)b * ND + lane] * fc_pre_w[lane]
            + i_vec[(size_t)b * ND + lane] * fc_pre_w[ND + lane];
#pragma unroll
    for (int off = 32; off; off >>= 1) v += __shfl_xor(v, off);
    if (lane == 0) out[b] = fmaxf(v + fc_pre_b[0], 0.f);
}

// ---------------------------------------------------------------------------
extern "C" void kernel_launch(void* const* d_in, const int* in_sizes, int n_in,
                              void* d_out, int out_size, void* d_ws, size_t ws_size,
                              hipStream_t stream) {
    (void)in_sizes; (void)n_in; (void)out_size; (void)ws_size;

    const int*   user         = (const int*)d_in[0];
    const int*   item         = (const int*)d_in[1];
    const float* user_r_topic = (const float*)d_in[2];
    const float* item_r_topic = (const float*)d_in[3];
    const float* user_embed_w = (const float*)d_in[4];
    const float* item_embed_w = (const float*)d_in[5];
    const float* user_att_w   = (const float*)d_in[6];
    const float* item_att_w   = (const float*)d_in[7];
    const float* topic_w      = (const float*)d_in[8];
    const float* fc_u_w       = (const float*)d_in[9];
    const float* fc_u_b       = (const float*)d_in[10];
    const float* fc_ru_w      = (const float*)d_in[11];
    const float* fc_ru_b      = (const float*)d_in[12];
    const float* fc_i_w       = (const float*)d_in[13];
    const float* fc_i_b       = (const float*)d_in[14];
    const float* fc_ri_w      = (const float*)d_in[15];
    const float* fc_ri_b      = (const float*)d_in[16];
    const float* h_u_w        = (const float*)d_in[17];
    const float* h_u_b        = (const float*)d_in[18];
    const float* h_i_w        = (const float*)d_in[19];
    const float* h_i_b        = (const float*)d_in[20];
    const float* fc_pre_w     = (const float*)d_in[21];
    const float* fc_pre_b     = (const float*)d_in[22];

    // workspace layout
    unsigned short* bhi  = (unsigned short*)d_ws;      // 32768
    unsigned short* fuhi = bhi + 32768;                // 8192
    unsigned short* fihi = fuhi + 8192;                // 8192
    float* colsum = (float*)(fihi + 8192);             // 64
    float* u_vec  = colsum + 64;                       // NB*ND
    float* i_vec  = u_vec + NB * ND;                   // NB*ND

    prep_kernel<<<192, 256, 0, stream>>>(topic_w, fc_u_w, fc_ru_w, fc_i_w, fc_ri_w,
                                         bhi, fuhi, fihi);
    colsum_kernel<<<1, 256, 0, stream>>>(topic_w, colsum);

    branch_kernel<<<2 * NB, 256, 0, stream>>>(
        user, item, user_r_topic, item_r_topic,
        user_embed_w, item_embed_w, user_att_w, item_att_w,
        bhi, fuhi, fihi,
        fc_u_b, fc_ru_b, fc_i_b, fc_ri_b,
        h_u_w, h_u_b, h_i_w, h_i_b,
        colsum, u_vec, i_vec);

    final_kernel<<<NB, 64, 0, stream>>>(u_vec, i_vec, fc_pre_w, fc_pre_b,
                                        (float*)d_out);
}

// Round 18
// 124.909 us; speedup vs baseline: 1.4663x; 1.0640x over previous
//
#include <hip/hip_runtime.h>
#include <cstdint>
#include <cstddef>

#define NB 2048
#define NT 512
#define ND 64
#define NR 50
#define NE 2             // batch elements per block
#define REVP 68          // review row stride (floats)
#define AHALF 25600      // A-half LDS bytes per elem: 50 rows x 512B
#define BQ 16384         // B-quarter LDS bytes

typedef __attribute__((ext_vector_type(8))) short bf16x8;
typedef __attribute__((ext_vector_type(4))) float f32x4;

__device__ inline unsigned short f2bf_rne(float x) {
    unsigned int u = __float_as_uint(x);
    u += 0x7fffu + ((u >> 16) & 1u);
    return (unsigned short)(u >> 16);
}

__device__ inline bf16x8 cvt8_rne(float4 v0, float4 v1) {
    union { unsigned int u[4]; bf16x8 v; } P;
    asm("v_cvt_pk_bf16_f32 %0, %1, %2" : "=v"(P.u[0]) : "v"(v0.x), "v"(v0.y));
    asm("v_cvt_pk_bf16_f32 %0, %1, %2" : "=v"(P.u[1]) : "v"(v0.z), "v"(v0.w));
    asm("v_cvt_pk_bf16_f32 %0, %1, %2" : "=v"(P.u[2]) : "v"(v1.x), "v"(v1.y));
    asm("v_cvt_pk_bf16_f32 %0, %1, %2" : "=v"(P.u[3]) : "v"(v1.z), "v"(v1.w));
    return P.v;
}

__device__ inline void gload16(const void* gsrc, void* ldst) {
    __builtin_amdgcn_global_load_lds(
        (const __attribute__((address_space(1))) unsigned int*)gsrc,
        (__attribute__((address_space(3))) unsigned int*)ldst, 16, 0, 0);
}

// ---------------------------------------------------------------------------
__global__ __launch_bounds__(256) void prep_kernel(
    const float* __restrict__ tw,
    const float* __restrict__ fc_u_w, const float* __restrict__ fc_ru_w,
    const float* __restrict__ fc_i_w, const float* __restrict__ fc_ri_w,
    unsigned short* __restrict__ bhi,
    unsigned short* __restrict__ fuhi, unsigned short* __restrict__ fihi)
{
    int i = blockIdx.x * 256 + threadIdx.x;          // 192*256 = 49152
    if (i < 32768) {
        int j  = i & 7;
        int l  = (i >> 3) & 63;
        int n  = (i >> 9) & 3;
        int kk = i >> 11;                            // 0..15
        int t = kk * 32 + ((l >> 4) << 3) + j;
        int d = n * 16 + (l & 15);
        bhi[i] = f2bf_rne(tw[t * ND + d]);
    } else {
        int q = i - 32768;                           // 0..16383
        int br = q >> 13;                            // 0 user, 1 item
        int e = q & 8191;
        int j  = e & 7;
        int l  = (e >> 3) & 63;
        int n  = (e >> 9) & 3;
        int kk = e >> 11;                            // 0..3
        int k = kk * 32 + ((l >> 4) << 3) + j;       // 0..127
        int col = n * 16 + (l & 15);
        const float* W = (k < 64) ? (br ? fc_ri_w : fc_ru_w)
                                  : (br ? fc_i_w  : fc_u_w);
        unsigned short hi = f2bf_rne(W[(k & 63) * ND + col]);
        if (br) fihi[e] = hi; else fuhi[e] = hi;
    }
}

// ---------------------------------------------------------------------------
__global__ __launch_bounds__(256) void colsum_kernel(const float* __restrict__ tw,
                                                     float* __restrict__ colsum) {
    __shared__ float part[4][ND];
    int d = threadIdx.x & 63, p = threadIdx.x >> 6;
    float s = 0.f;
    for (int t = p; t < NT; t += 4) s += tw[t * ND + d];
    part[p][d] = s;
    __syncthreads();
    if (threadIdx.x < ND)
        colsum[d] = part[0][d] + part[1][d] + part[2][d] + part[3][d];
}

// pinned issue: tag T, elem e, row-slot i, half hh (1KB contiguous/instr)
#define AISSUE(T, e, i, hh)                                                    \
    int r_##T##_##i = (i) * 4 + wave;                                          \
    r_##T##_##i = r_##T##_##i > NR - 1 ? NR - 1 : r_##T##_##i;                 \
    float4 dA_##T##_##i;                                                       \
    {                                                                          \
        const float* _p = arowp[e] + (size_t)r_##T##_##i * NT + (hh) * 256 + lane * 4; \
        asm volatile("global_load_dwordx4 %0, %1, off"                         \
                     : "=v"(dA_##T##_##i) : "v"(_p) : "memory");               \
    }
#define AROW(T, e, hh)                                                         \
    AISSUE(T, e, 0, hh)  AISSUE(T, e, 1, hh)  AISSUE(T, e, 2, hh)              \
    AISSUE(T, e, 3, hh)  AISSUE(T, e, 4, hh)  AISSUE(T, e, 5, hh)              \
    AISSUE(T, e, 6, hh)  AISSUE(T, e, 7, hh)  AISSUE(T, e, 8, hh)              \
    AISSUE(T, e, 9, hh)  AISSUE(T, e, 10, hh) AISSUE(T, e, 11, hh)             \
    AISSUE(T, e, 12, hh)

// interlocked retire+convert, swizzled ds_write into elem e's A region
#define ACONSUME(T, e, i, N)                                                   \
    {                                                                          \
        unsigned int _o0, _o1;                                                 \
        asm volatile("s_waitcnt vmcnt(" #N ")\n\t"                             \
                     "v_cvt_pk_bf16_f32 %0, %2, %3\n\t"                        \
                     "v_cvt_pk_bf16_f32 %1, %4, %5"                            \
                     : "=&v"(_o0), "=&v"(_o1)                                  \
                     : "v"(dA_##T##_##i.x), "v"(dA_##T##_##i.y),               \
                       "v"(dA_##T##_##i.z), "v"(dA_##T##_##i.w)                \
                     : "memory");                                              \
        uint2 _w; _w.x = _o0; _w.y = _o1;                                      \
        *reinterpret_cast<uint2*>(arena + (e) * AHALF + r_##T##_##i * 512 +    \
            ((lane ^ ((r_##T##_##i & 7) << 1)) * 8)) = _w;                     \
    }
// elem0 retire (13 elem1 loads still behind): vmcnt(25-i)
#define ACROW0(T)                                                              \
    ACONSUME(T, 0, 0, 25) ACONSUME(T, 0, 1, 24) ACONSUME(T, 0, 2, 23)          \
    ACONSUME(T, 0, 3, 22) ACONSUME(T, 0, 4, 21) ACONSUME(T, 0, 5, 20)          \
    ACONSUME(T, 0, 6, 19) ACONSUME(T, 0, 7, 18) ACONSUME(T, 0, 8, 17)          \
    ACONSUME(T, 0, 9, 16) ACONSUME(T, 0, 10, 15) ACONSUME(T, 0, 11, 14)        \
    ACONSUME(T, 0, 12, 13)
// elem1 retire: vmcnt(12-i); final 0 also drains B-quarter gload_lds
#define ACROW1(T)                                                              \
    ACONSUME(T, 1, 0, 12) ACONSUME(T, 1, 1, 11) ACONSUME(T, 1, 2, 10)          \
    ACONSUME(T, 1, 3, 9)  ACONSUME(T, 1, 4, 8)  ACONSUME(T, 1, 5, 7)           \
    ACONSUME(T, 1, 6, 6)  ACONSUME(T, 1, 7, 5)  ACONSUME(T, 1, 8, 4)           \
    ACONSUME(T, 1, 9, 3)  ACONSUME(T, 1, 10, 2) ACONSUME(T, 1, 11, 1)          \
    ACONSUME(T, 1, 12, 0)

// ---------------------------------------------------------------------------
// Block = 4 waves x 2 batch elements (grid 2048), 2 blocks/CU.
// Per K-half: B-quarter staged (16KB, reused by both elems), 26 pinned A
// loads all in flight (group-retired vmcnt(25..13)/(12..0)); pure-LDS MFMA
// with B-frag reuse x2. B/fc global traffic halved vs r17; A L3 locality
// preserved (half-split, not quarter-split).
__global__ __launch_bounds__(256, 2) void branch_kernel(
    const int* __restrict__ user, const int* __restrict__ item,
    const float* __restrict__ user_r_topic, const float* __restrict__ item_r_topic,
    const float* __restrict__ user_embed_w, const float* __restrict__ item_embed_w,
    const float* __restrict__ user_att_w, const float* __restrict__ item_att_w,
    const unsigned short* __restrict__ bhi,
    const unsigned short* __restrict__ fuhi, const unsigned short* __restrict__ fihi,
    const float* __restrict__ fc_u_b, const float* __restrict__ fc_ru_b,
    const float* __restrict__ fc_i_b, const float* __restrict__ fc_ri_b,
    const float* __restrict__ h_u_w, const float* __restrict__ h_u_b,
    const float* __restrict__ h_i_w, const float* __restrict__ h_i_b,
    const float* __restrict__ colsum,
    float* __restrict__ u_vec, float* __restrict__ i_vec)
{
    // arena: A elem0 [0,25600) | A elem1 [25600,51200) | B-quarter [51200,67584)
    // rev[2][50][68] f32 (54.4 KB) overlays arena after the K-loop.
    __shared__ __align__(16) unsigned char arena[NE * AHALF + BQ];
    __shared__ float lds_logit[NE][NR + 2];

    const int tid = threadIdx.x, wave = tid >> 6, lane = tid & 63;
    const int g = lane >> 4, c16 = lane & 15;

    const int E0 = blockIdx.x * NE;         // 2 consecutive elems, same branch
    const int branch = E0 >> 11;            // 0 = user, 1 = item

    const int*   ids     = branch ? item           : user;
    const float* r_topic = branch ? item_r_topic   : user_r_topic;
    const float* emb_w   = branch ? item_embed_w   : user_embed_w;
    const float* att_w   = branch ? item_att_w     : user_att_w;
    const unsigned short* fhi = branch ? fihi : fuhi;
    const float* fc_a_b  = branch ? fc_i_b         : fc_u_b;
    const float* fc_r_b  = branch ? fc_ri_b        : fc_ru_b;
    const float* h_w     = branch ? h_i_w          : h_u_w;
    const float* h_b     = branch ? h_i_b          : h_u_b;
    float*       out_vec = branch ? i_vec          : u_vec;

    const int rowg = wave * 16 + c16;
    const int rowc = rowg < NR ? rowg : NR - 1;
    unsigned char* blds = arena + NE * AHALF;

    int bidx[NE], idv[NE];
    const float* arowp[NE];
#pragma unroll
    for (int e = 0; e < NE; ++e) {
        bidx[e] = (E0 + e) & (NB - 1);
        idv[e]  = ids[bidx[e]];
        arowp[e] = r_topic + (size_t)bidx[e] * NR * NT;
    }

    // B-quarter stage: 4 gload16/thread (16 KB block-wide); qq = 0..3
    auto stageBq = [&](int qq) {
        const unsigned char* src = (const unsigned char*)bhi + (size_t)qq * BQ;
#pragma unroll
        for (int i = 0; i < 4; ++i) {
            size_t off = (size_t)(i * 256 + tid) * 16;
            gload16(src + off, blds + off);
        }
    };

    f32x4 acc[NE][4];
#pragma unroll
    for (int e = 0; e < NE; ++e)
#pragma unroll
        for (int n = 0; n < 4; ++n) acc[e][n] = (f32x4){0.f, 0.f, 0.f, 0.f};

    // compute one kstep: local B index kl (0..3 in quarter), A frag index ka
    auto kstep = [&](int kl, int ka) {
        bf16x8 af[NE];
#pragma unroll
        for (int e = 0; e < NE; ++e)
            af[e] = *reinterpret_cast<const bf16x8*>(
                arena + e * AHALF + rowc * 512 + (((ka * 4 + g) ^ (rowc & 7)) << 4));
#pragma unroll
        for (int n = 0; n < 4; ++n) {
            bf16x8 bh = *reinterpret_cast<const bf16x8*>(
                blds + (size_t)((kl * 4 + n) * 64 + lane) * 16);
#pragma unroll
            for (int e = 0; e < NE; ++e)
                acc[e][n] = __builtin_amdgcn_mfma_f32_16x16x32_bf16(af[e], bh, acc[e][n], 0, 0, 0);
        }
    };

    // ================= half 0 =================
    stageBq(0);
    AROW(h0a, 0, 0) AROW(h0b, 1, 0)       // 26 pinned A loads in flight
    ACROW0(h0a) ACROW1(h0b)               // retire + cvt + swizzled ds_write
    __syncthreads();                      // A half0 (both elems) + Bq0 resident
#pragma unroll
    for (int kl = 0; kl < 4; ++kl) kstep(kl, kl);
    __syncthreads();                      // Bq0 reads done
    stageBq(1);
    asm volatile("s_waitcnt vmcnt(0)" ::: "memory");
    __builtin_amdgcn_sched_barrier(0);
    __syncthreads();                      // Bq1 resident
#pragma unroll
    for (int kl = 0; kl < 4; ++kl) kstep(kl, kl + 4);
    __syncthreads();                      // A half0 + Bq1 reads done

    // ================= half 1 =================
    stageBq(2);
    AROW(h1a, 0, 1) AROW(h1b, 1, 1)
    ACROW0(h1a) ACROW1(h1b)
    __syncthreads();                      // A half1 + Bq2 resident
#pragma unroll
    for (int kl = 0; kl < 4; ++kl) kstep(kl, kl);
    __syncthreads();                      // Bq2 reads done
    stageBq(3);
    asm volatile("s_waitcnt vmcnt(0)" ::: "memory");
    __builtin_amdgcn_sched_barrier(0);
    __syncthreads();                      // Bq3 resident
#pragma unroll
    for (int kl = 0; kl < 4; ++kl) kstep(kl, kl + 4);

    __syncthreads();                      // all LDS reads done -> overlay rev
    float (*rev)[NR][REVP] = reinterpret_cast<float(*)[NR][REVP]>(arena);
#pragma unroll
    for (int e = 0; e < NE; ++e)
#pragma unroll
        for (int n = 0; n < 4; ++n)
#pragma unroll
            for (int r4 = 0; r4 < 4; ++r4) {
                int r = wave * 16 + g * 4 + r4;
                if (r < NR) rev[e][r][n * 16 + c16] = acc[e][n][r4];
            }
    // no barrier: epilogue reads only this wave's own rows

    // ---- epilogue s-matmul: s[e][50x64] = review@fcR + att@fcA (K=128) ----
    f32x4 s4[NE][4];
#pragma unroll
    for (int e = 0; e < NE; ++e)
#pragma unroll
        for (int n = 0; n < 4; ++n) s4[e][n] = (f32x4){0.f, 0.f, 0.f, 0.f};

#pragma unroll
    for (int kk2 = 0; kk2 < 4; ++kk2) {
        bf16x8 bh[4];
#pragma unroll
        for (int n = 0; n < 4; ++n)
            bh[n] = *(reinterpret_cast<const bf16x8*>(fhi + (size_t)(kk2 * 4 + n) * 512) + lane);
#pragma unroll
        for (int e = 0; e < NE; ++e) {
            bf16x8 ah;
            if (kk2 < 2) {
                const float* rp = &rev[e][rowc][kk2 * 32 + g * 8];
                ah = cvt8_rne(*reinterpret_cast<const float4*>(rp),
                              *reinterpret_cast<const float4*>(rp + 4));
            } else {
                const float* ap = att_w + (size_t)idv[e] * ND + (kk2 - 2) * 32 + g * 8;
                ah = cvt8_rne(*reinterpret_cast<const float4*>(ap),
                              *reinterpret_cast<const float4*>(ap + 4));
            }
#pragma unroll
            for (int n = 0; n < 4; ++n)
                s4[e][n] = __builtin_amdgcn_mfma_f32_16x16x32_bf16(ah, bh[n], s4[e][n], 0, 0, 0);
        }
    }

    // bias + relu + dot with h_w, 16-lane reduce -> logits (per element)
    const float hb = h_b[0];
#pragma unroll
    for (int e = 0; e < NE; ++e) {
        float p0 = 0.f, p1 = 0.f, p2 = 0.f, p3 = 0.f;
#pragma unroll
        for (int n = 0; n < 4; ++n) {
            float hwn = h_w[n * 16 + c16];
            float bs = fc_r_b[n * 16 + c16] + fc_a_b[n * 16 + c16];
            p0 = fmaf(fmaxf(s4[e][n][0] + bs, 0.f), hwn, p0);
            p1 = fmaf(fmaxf(s4[e][n][1] + bs, 0.f), hwn, p1);
            p2 = fmaf(fmaxf(s4[e][n][2] + bs, 0.f), hwn, p2);
            p3 = fmaf(fmaxf(s4[e][n][3] + bs, 0.f), hwn, p3);
        }
#pragma unroll
        for (int off = 1; off < 16; off <<= 1) {
            p0 += __shfl_xor(p0, off);
            p1 += __shfl_xor(p1, off);
            p2 += __shfl_xor(p2, off);
            p3 += __shfl_xor(p3, off);
        }
        if (c16 == 0) {
            int rb = wave * 16 + g * 4;
            if (rb + 0 < NR) lds_logit[e][rb + 0] = p0 + hb;
            if (rb + 1 < NR) lds_logit[e][rb + 1] = p1 + hb;
            if (rb + 2 < NR) lds_logit[e][rb + 2] = p2 + hb;
            if (rb + 3 < NR) lds_logit[e][rb + 3] = p3 + hb;
        }
    }
    __syncthreads();   // publish rev rows + logits

    // softmax + pooling + colsum scale + emb add (wave e -> elem e)
    if (wave < NE) {
        const int e = wave;
        const int b = bidx[e];
        const int id = idv[e];
        float m = -1e30f;
        for (int r = 0; r < NR; ++r) m = fmaxf(m, lds_logit[e][r]);
        float sum = 0.f;
        for (int r = 0; r < NR; ++r) sum += __expf(lds_logit[e][r] - m);
        float inv = 1.f / sum;
        float feat = 0.f;
        for (int r = 0; r < NR; ++r)
            feat = fmaf(__expf(lds_logit[e][r] - m), rev[e][r][lane], feat);
        feat *= inv;
        out_vec[(size_t)b * ND + lane] = feat * colsum[lane] + emb_w[(size_t)id * ND + lane];
    }
}

// ---------------------------------------------------------------------------
__global__ __launch_bounds__(64) void final_kernel(
    const float* __restrict__ u_vec, const float* __restrict__ i_vec,
    const float* __restrict__ fc_pre_w, const float* __restrict__ fc_pre_b,
    float* __restrict__ out)
{
    int b = blockIdx.x, lane = threadIdx.x;
    float v = u_vec[(size_t)b * ND + lane] * fc_pre_w[lane]
            + i_vec[(size_t)b * ND + lane] * fc_pre_w[ND + lane];
#pragma unroll
    for (int off = 32; off; off >>= 1) v += __shfl_xor(v, off);
    if (lane == 0) out[b] = fmaxf(v + fc_pre_b[0], 0.f);
}

// ---------------------------------------------------------------------------
extern "C" void kernel_launch(void* const* d_in, const int* in_sizes, int n_in,
                              void* d_out, int out_size, void* d_ws, size_t ws_size,
                              hipStream_t stream) {
    (void)in_sizes; (void)n_in; (void)out_size; (void)ws_size;

    const int*   user         = (const int*)d_in[0];
    const int*   item         = (const int*)d_in[1];
    const float* user_r_topic = (const float*)d_in[2];
    const float* item_r_topic = (const float*)d_in[3];
    const float* user_embed_w = (const float*)d_in[4];
    const float* item_embed_w = (const float*)d_in[5];
    const float* user_att_w   = (const float*)d_in[6];
    const float* item_att_w   = (const float*)d_in[7];
    const float* topic_w      = (const float*)d_in[8];
    const float* fc_u_w       = (const float*)d_in[9];
    const float* fc_u_b       = (const float*)d_in[10];
    const float* fc_ru_w      = (const float*)d_in[11];
    const float* fc_ru_b      = (const float*)d_in[12];
    const float* fc_i_w       = (const float*)d_in[13];
    const float* fc_i_b       = (const float*)d_in[14];
    const float* fc_ri_w      = (const float*)d_in[15];
    const float* fc_ri_b      = (const float*)d_in[16];
    const float* h_u_w        = (const float*)d_in[17];
    const float* h_u_b        = (const float*)d_in[18];
    const float* h_i_w        = (const float*)d_in[19];
    const float* h_i_b        = (const float*)d_in[20];
    const float* fc_pre_w     = (const float*)d_in[21];
    const float* fc_pre_b     = (const float*)d_in[22];

    // workspace layout
    unsigned short* bhi  = (unsigned short*)d_ws;      // 32768
    unsigned short* fuhi = bhi + 32768;                // 8192
    unsigned short* fihi = fuhi + 8192;                // 8192
    float* colsum = (float*)(fihi + 8192);             // 64
    float* u_vec  = colsum + 64;                       // NB*ND
    float* i_vec  = u_vec + NB * ND;                   // NB*ND

    prep_kernel<<<192, 256, 0, stream>>>(topic_w, fc_u_w, fc_ru_w, fc_i_w, fc_ri_w,
                                         bhi, fuhi, fihi);
    colsum_kernel<<<1, 256, 0, stream>>>(topic_w, colsum);

    branch_kernel<<<(2 * NB) / NE, 256, 0, stream>>>(
        user, item, user_r_topic, item_r_topic,
        user_embed_w, item_embed_w, user_att_w, item_att_w,
        bhi, fuhi, fihi,
        fc_u_b, fc_ru_b, fc_i_b, fc_ri_b,
        h_u_w, h_u_b, h_i_w, h_i_b,
        colsum, u_vec, i_vec);

    final_kernel<<<NB, 64, 0, stream>>>(u_vec, i_vec, fc_pre_w, fc_pre_b,
                                        (float*)d_out);
}

// Round 19
// 124.072 us; speedup vs baseline: 1.4762x; 1.0067x over previous
//
#include <hip/hip_runtime.h>
#include <cstdint>
#include <cstddef>

#define NB 2048
#define NT 512
#define ND 64
#define NR 50
#define NE 2             // batch elements per block
#define REVP 68          // review row stride (floats)
#define BH 32768         // B-half LDS bytes

typedef __attribute__((ext_vector_type(8))) short bf16x8;
typedef __attribute__((ext_vector_type(4))) float f32x4;

__device__ inline unsigned short f2bf_rne(float x) {
    unsigned int u = __float_as_uint(x);
    u += 0x7fffu + ((u >> 16) & 1u);
    return (unsigned short)(u >> 16);
}

__device__ inline bf16x8 cvt8_rne(float4 v0, float4 v1) {
    union { unsigned int u[4]; bf16x8 v; } P;
    asm("v_cvt_pk_bf16_f32 %0, %1, %2" : "=v"(P.u[0]) : "v"(v0.x), "v"(v0.y));
    asm("v_cvt_pk_bf16_f32 %0, %1, %2" : "=v"(P.u[1]) : "v"(v0.z), "v"(v0.w));
    asm("v_cvt_pk_bf16_f32 %0, %1, %2" : "=v"(P.u[2]) : "v"(v1.x), "v"(v1.y));
    asm("v_cvt_pk_bf16_f32 %0, %1, %2" : "=v"(P.u[3]) : "v"(v1.z), "v"(v1.w));
    return P.v;
}

__device__ inline void gload16(const void* gsrc, void* ldst) {
    __builtin_amdgcn_global_load_lds(
        (const __attribute__((address_space(1))) unsigned int*)gsrc,
        (__attribute__((address_space(3))) unsigned int*)ldst, 16, 0, 0);
}

// ---------------------------------------------------------------------------
__global__ __launch_bounds__(256) void prep_kernel(
    const float* __restrict__ tw,
    const float* __restrict__ fc_u_w, const float* __restrict__ fc_ru_w,
    const float* __restrict__ fc_i_w, const float* __restrict__ fc_ri_w,
    unsigned short* __restrict__ bhi,
    unsigned short* __restrict__ fuhi, unsigned short* __restrict__ fihi)
{
    int i = blockIdx.x * 256 + threadIdx.x;          // 192*256 = 49152
    if (i < 32768) {
        int j  = i & 7;
        int l  = (i >> 3) & 63;
        int n  = (i >> 9) & 3;
        int kk = i >> 11;                            // 0..15
        int t = kk * 32 + ((l >> 4) << 3) + j;
        int d = n * 16 + (l & 15);
        bhi[i] = f2bf_rne(tw[t * ND + d]);
    } else {
        int q = i - 32768;                           // 0..16383
        int br = q >> 13;                            // 0 user, 1 item
        int e = q & 8191;
        int j  = e & 7;
        int l  = (e >> 3) & 63;
        int n  = (e >> 9) & 3;
        int kk = e >> 11;                            // 0..3
        int k = kk * 32 + ((l >> 4) << 3) + j;       // 0..127
        int col = n * 16 + (l & 15);
        const float* W = (k < 64) ? (br ? fc_ri_w : fc_ru_w)
                                  : (br ? fc_i_w  : fc_u_w);
        unsigned short hi = f2bf_rne(W[(k & 63) * ND + col]);
        if (br) fihi[e] = hi; else fuhi[e] = hi;
    }
}

// ---------------------------------------------------------------------------
__global__ __launch_bounds__(256) void colsum_kernel(const float* __restrict__ tw,
                                                     float* __restrict__ colsum) {
    __shared__ float part[4][ND];
    int d = threadIdx.x & 63, p = threadIdx.x >> 6;
    float s = 0.f;
    for (int t = p; t < NT; t += 4) s += tw[t * ND + d];
    part[p][d] = s;
    __syncthreads();
    if (threadIdx.x < ND)
        colsum[d] = part[0][d] + part[1][d] + part[2][d] + part[3][d];
}

// pinned issue of ONE kstep's A fragment (8 floats of this lane's own row)
#define AISS2(T, e, COL)                                                       \
    float4 aA_##T##_0, aA_##T##_1;                                             \
    {                                                                          \
        const float* _p = arowp[e] + (size_t)rowc * NT + (COL);                \
        asm volatile("global_load_dwordx4 %0, %1, off"                         \
                     : "=v"(aA_##T##_0) : "v"(_p) : "memory");                 \
        asm volatile("global_load_dwordx4 %0, %1, off"                         \
                     : "=v"(aA_##T##_1) : "v"(_p + 4) : "memory");             \
    }
// 8 loads = one elem's quarter (4 ksteps)
#define AISS8(T, e, h, qh)                                                     \
    AISS2(T##_0, e, (h) * 256 + ((qh) * 4 + 0) * 32 + g * 8)                   \
    AISS2(T##_1, e, (h) * 256 + ((qh) * 4 + 1) * 32 + g * 8)                   \
    AISS2(T##_2, e, (h) * 256 + ((qh) * 4 + 2) * 32 + g * 8)                   \
    AISS2(T##_3, e, (h) * 256 + ((qh) * 4 + 3) * 32 + g * 8)

// interlocked retire+convert -> bf16x8 fragment fr_<T>.v
#define ARET(T, N)                                                             \
    union { unsigned int u[4]; bf16x8 v; } fr_##T;                             \
    asm volatile("s_waitcnt vmcnt(" #N ")\n\t"                                 \
                 "v_cvt_pk_bf16_f32 %0, %4, %5\n\t"                            \
                 "v_cvt_pk_bf16_f32 %1, %6, %7\n\t"                            \
                 "v_cvt_pk_bf16_f32 %2, %8, %9\n\t"                            \
                 "v_cvt_pk_bf16_f32 %3, %10, %11"                              \
                 : "=&v"(fr_##T.u[0]), "=&v"(fr_##T.u[1]),                     \
                   "=&v"(fr_##T.u[2]), "=&v"(fr_##T.u[3])                      \
                 : "v"(aA_##T##_0.x), "v"(aA_##T##_0.y),                       \
                   "v"(aA_##T##_0.z), "v"(aA_##T##_0.w),                       \
                   "v"(aA_##T##_1.x), "v"(aA_##T##_1.y),                       \
                   "v"(aA_##T##_1.z), "v"(aA_##T##_1.w)                        \
                 : "memory");
// retire a full 16-load quarter (e0 then e1), ladder 14..0
#define ARETQ(T0, T1)                                                          \
    ARET(T0##_0, 14) ARET(T0##_1, 12) ARET(T0##_2, 10) ARET(T0##_3, 8)         \
    ARET(T1##_0, 6)  ARET(T1##_1, 4)  ARET(T1##_2, 2)  ARET(T1##_3, 0)
// compute one quarter (4 ksteps, both elems)
#define QCOMP(T0, T1, qh)                                                      \
    kstep((qh) * 4 + 0, fr_##T0##_0.v, fr_##T1##_0.v);                         \
    kstep((qh) * 4 + 1, fr_##T0##_1.v, fr_##T1##_1.v);                         \
    kstep((qh) * 4 + 2, fr_##T0##_2.v, fr_##T1##_2.v);                         \
    kstep((qh) * 4 + 3, fr_##T0##_3.v, fr_##T1##_3.v);

// ---------------------------------------------------------------------------
// Block = 4 waves x 2 batch elements (grid 2048), 3 blocks/CU (12 waves).
// A: NO LDS -- pinned global->reg loads in MFMA fragment layout (each lane
// reads 8 floats of its own row), fused vmcnt+cvt retirement. LDS holds only
// the B-half (32KB, reused by both elems) + logits. B barriers: 2 per half.
__global__ __launch_bounds__(256, 3) void branch_kernel(
    const int* __restrict__ user, const int* __restrict__ item,
    const float* __restrict__ user_r_topic, const float* __restrict__ item_r_topic,
    const float* __restrict__ user_embed_w, const float* __restrict__ item_embed_w,
    const float* __restrict__ user_att_w, const float* __restrict__ item_att_w,
    const unsigned short* __restrict__ bhi,
    const unsigned short* __restrict__ fuhi, const unsigned short* __restrict__ fihi,
    const float* __restrict__ fc_u_b, const float* __restrict__ fc_ru_b,
    const float* __restrict__ fc_i_b, const float* __restrict__ fc_ri_b,
    const float* __restrict__ h_u_w, const float* __restrict__ h_u_b,
    const float* __restrict__ h_i_w, const float* __restrict__ h_i_b,
    const float* __restrict__ colsum,
    float* __restrict__ u_vec, float* __restrict__ i_vec)
{
    // arena: B-half frag order [0, 32768). rev[2][50][68] (27.2KB) overlays it.
    __shared__ __align__(16) unsigned char arena[BH];
    __shared__ float lds_logit[NE][NR + 2];

    const int tid = threadIdx.x, wave = tid >> 6, lane = tid & 63;
    const int g = lane >> 4, c16 = lane & 15;

    const int E0 = blockIdx.x * NE;         // 2 consecutive elems, same branch
    const int branch = E0 >> 11;            // 0 = user, 1 = item

    const int*   ids     = branch ? item           : user;
    const float* r_topic = branch ? item_r_topic   : user_r_topic;
    const float* emb_w   = branch ? item_embed_w   : user_embed_w;
    const float* att_w   = branch ? item_att_w     : user_att_w;
    const unsigned short* fhi = branch ? fihi : fuhi;
    const float* fc_a_b  = branch ? fc_i_b         : fc_u_b;
    const float* fc_r_b  = branch ? fc_ri_b        : fc_ru_b;
    const float* h_w     = branch ? h_i_w          : h_u_w;
    const float* h_b     = branch ? h_i_b          : h_u_b;
    float*       out_vec = branch ? i_vec          : u_vec;

    const int rowg = wave * 16 + c16;
    const int rowc = rowg < NR ? rowg : NR - 1;

    int bidx[NE], idv[NE];
    const float* arowp[NE];
#pragma unroll
    for (int e = 0; e < NE; ++e) {
        bidx[e] = (E0 + e) & (NB - 1);
        idv[e]  = ids[bidx[e]];
        arowp[e] = r_topic + (size_t)bidx[e] * NR * NT;
    }

    // stage one 32KB B-half (8 x 16B per thread, coalesced)
    auto stageB = [&](int h) {
        const unsigned char* src = (const unsigned char*)bhi + (size_t)h * BH;
#pragma unroll
        for (int i = 0; i < 8; ++i) {
            size_t off = (size_t)(i * 256 + tid) * 16;
            gload16(src + off, arena + off);
        }
    };

    f32x4 acc[NE][4];
#pragma unroll
    for (int e = 0; e < NE; ++e)
#pragma unroll
        for (int n = 0; n < 4; ++n) acc[e][n] = (f32x4){0.f, 0.f, 0.f, 0.f};

    // one kstep: klq = kstep index within half (0..7); f0/f1 = A frags
    auto kstep = [&](int klq, bf16x8 f0, bf16x8 f1) {
#pragma unroll
        for (int n = 0; n < 4; ++n) {
            bf16x8 bh = *reinterpret_cast<const bf16x8*>(
                arena + (size_t)((klq * 4 + n) * 64 + lane) * 16);
            acc[0][n] = __builtin_amdgcn_mfma_f32_16x16x32_bf16(f0, bh, acc[0][n], 0, 0, 0);
            acc[1][n] = __builtin_amdgcn_mfma_f32_16x16x32_bf16(f1, bh, acc[1][n], 0, 0, 0);
        }
    };

    // ================= half 0 =================
    stageB(0);                              // [8 outstanding]
    AISS8(h0q0e0, 0, 0, 0) AISS8(h0q0e1, 1, 0, 0)   // [24]
    asm volatile("s_waitcnt vmcnt(16)" ::: "memory");  // B half0 landed
    __builtin_amdgcn_sched_barrier(0);
    __builtin_amdgcn_s_barrier();           // B half0 visible block-wide
    __builtin_amdgcn_sched_barrier(0);
    ARETQ(h0q0e0, h0q0e1)                   // retire q0 A frags
    QCOMP(h0q0e0, h0q0e1, 0)
    AISS8(h0q1e0, 0, 0, 1) AISS8(h0q1e1, 1, 0, 1)   // [16]
    ARETQ(h0q1e0, h0q1e1)
    QCOMP(h0q1e0, h0q1e1, 1)
    __builtin_amdgcn_sched_barrier(0);
    __builtin_amdgcn_s_barrier();           // all waves done reading B half0
    __builtin_amdgcn_sched_barrier(0);

    // ================= half 1 =================
    stageB(1);                              // [8]
    AISS8(h1q0e0, 0, 1, 0) AISS8(h1q0e1, 1, 1, 0)   // [24]
    asm volatile("s_waitcnt vmcnt(16)" ::: "memory");  // B half1 landed
    __builtin_amdgcn_sched_barrier(0);
    __builtin_amdgcn_s_barrier();
    __builtin_amdgcn_sched_barrier(0);
    ARETQ(h1q0e0, h1q0e1)
    QCOMP(h1q0e0, h1q0e1, 0)
    AISS8(h1q1e0, 0, 1, 1) AISS8(h1q1e1, 1, 1, 1)
    ARETQ(h1q1e0, h1q1e1)
    QCOMP(h1q1e0, h1q1e1, 1)

    __syncthreads();                        // all B reads done -> overlay rev
    float (*rev)[NR][REVP] = reinterpret_cast<float(*)[NR][REVP]>(arena);
#pragma unroll
    for (int e = 0; e < NE; ++e)
#pragma unroll
        for (int n = 0; n < 4; ++n)
#pragma unroll
            for (int r4 = 0; r4 < 4; ++r4) {
                int r = wave * 16 + g * 4 + r4;
                if (r < NR) rev[e][r][n * 16 + c16] = acc[e][n][r4];
            }
    // no barrier: epilogue reads only this wave's own rows

    // ---- epilogue s-matmul: s[e][50x64] = review@fcR + att@fcA (K=128) ----
    f32x4 s4[NE][4];
#pragma unroll
    for (int e = 0; e < NE; ++e)
#pragma unroll
        for (int n = 0; n < 4; ++n) s4[e][n] = (f32x4){0.f, 0.f, 0.f, 0.f};

#pragma unroll
    for (int kk2 = 0; kk2 < 4; ++kk2) {
        bf16x8 bh[4];
#pragma unroll
        for (int n = 0; n < 4; ++n)
            bh[n] = *(reinterpret_cast<const bf16x8*>(fhi + (size_t)(kk2 * 4 + n) * 512) + lane);
#pragma unroll
        for (int e = 0; e < NE; ++e) {
            bf16x8 ah;
            if (kk2 < 2) {
                const float* rp = &rev[e][rowc][kk2 * 32 + g * 8];
                ah = cvt8_rne(*reinterpret_cast<const float4*>(rp),
                              *reinterpret_cast<const float4*>(rp + 4));
            } else {
                const float* ap = att_w + (size_t)idv[e] * ND + (kk2 - 2) * 32 + g * 8;
                ah = cvt8_rne(*reinterpret_cast<const float4*>(ap),
                              *reinterpret_cast<const float4*>(ap + 4));
            }
#pragma unroll
            for (int n = 0; n < 4; ++n)
                s4[e][n] = __builtin_amdgcn_mfma_f32_16x16x32_bf16(ah, bh[n], s4[e][n], 0, 0, 0);
        }
    }

    // bias + relu + dot with h_w, 16-lane reduce -> logits (per element)
    const float hb = h_b[0];
#pragma unroll
    for (int e = 0; e < NE; ++e) {
        float p0 = 0.f, p1 = 0.f, p2 = 0.f, p3 = 0.f;
#pragma unroll
        for (int n = 0; n < 4; ++n) {
            float hwn = h_w[n * 16 + c16];
            float bs = fc_r_b[n * 16 + c16] + fc_a_b[n * 16 + c16];
            p0 = fmaf(fmaxf(s4[e][n][0] + bs, 0.f), hwn, p0);
            p1 = fmaf(fmaxf(s4[e][n][1] + bs, 0.f), hwn, p1);
            p2 = fmaf(fmaxf(s4[e][n][2] + bs, 0.f), hwn, p2);
            p3 = fmaf(fmaxf(s4[e][n][3] + bs, 0.f), hwn, p3);
        }
#pragma unroll
        for (int off = 1; off < 16; off <<= 1) {
            p0 += __shfl_xor(p0, off);
            p1 += __shfl_xor(p1, off);
            p2 += __shfl_xor(p2, off);
            p3 += __shfl_xor(p3, off);
        }
        if (c16 == 0) {
            int rb = wave * 16 + g * 4;
            if (rb + 0 < NR) lds_logit[e][rb + 0] = p0 + hb;
            if (rb + 1 < NR) lds_logit[e][rb + 1] = p1 + hb;
            if (rb + 2 < NR) lds_logit[e][rb + 2] = p2 + hb;
            if (rb + 3 < NR) lds_logit[e][rb + 3] = p3 + hb;
        }
    }
    __syncthreads();   // publish rev rows + logits

    // softmax + pooling + colsum scale + emb add (wave e -> elem e)
    if (wave < NE) {
        const int e = wave;
        const int b = bidx[e];
        const int id = idv[e];
        float m = -1e30f;
        for (int r = 0; r < NR; ++r) m = fmaxf(m, lds_logit[e][r]);
        float sum = 0.f;
        for (int r = 0; r < NR; ++r) sum += __expf(lds_logit[e][r] - m);
        float inv = 1.f / sum;
        float feat = 0.f;
        for (int r = 0; r < NR; ++r)
            feat = fmaf(__expf(lds_logit[e][r] - m), rev[e][r][lane], feat);
        feat *= inv;
        out_vec[(size_t)b * ND + lane] = feat * colsum[lane] + emb_w[(size_t)id * ND + lane];
    }
}

// ---------------------------------------------------------------------------
__global__ __launch_bounds__(64) void final_kernel(
    const float* __restrict__ u_vec, const float* __restrict__ i_vec,
    const float* __restrict__ fc_pre_w, const float* __restrict__ fc_pre_b,
    float* __restrict__ out)
{
    int b = blockIdx.x, lane = threadIdx.x;
    float v = u_vec[(size_t)b * ND + lane] * fc_pre_w[lane]
            + i_vec[(size_t)b * ND + lane] * fc_pre_w[ND + lane];
#pragma unroll
    for (int off = 32; off; off >>= 1) v += __shfl_xor(v, off);
    if (lane == 0) out[b] = fmaxf(v + fc_pre_b[0], 0.f);
}

// ---------------------------------------------------------------------------
extern "C" void kernel_launch(void* const* d_in, const int* in_sizes, int n_in,
                              void* d_out, int out_size, void* d_ws, size_t ws_size,
                              hipStream_t stream) {
    (void)in_sizes; (void)n_in; (void)out_size; (void)ws_size;

    const int*   user         = (const int*)d_in[0];
    const int*   item         = (const int*)d_in[1];
    const float* user_r_topic = (const float*)d_in[2];
    const float* item_r_topic = (const float*)d_in[3];
    const float* user_embed_w = (const float*)d_in[4];
    const float* item_embed_w = (const float*)d_in[5];
    const float* user_att_w   = (const float*)d_in[6];
    const float* item_att_w   = (const float*)d_in[7];
    const float* topic_w      = (const float*)d_in[8];
    const float* fc_u_w       = (const float*)d_in[9];
    const float* fc_u_b       = (const float*)d_in[10];
    const float* fc_ru_w      = (const float*)d_in[11];
    const float* fc_ru_b      = (const float*)d_in[12];
    const float* fc_i_w       = (const float*)d_in[13];
    const float* fc_i_b       = (const float*)d_in[14];
    const float* fc_ri_w      = (const float*)d_in[15];
    const float* fc_ri_b      = (const float*)d_in[16];
    const float* h_u_w        = (const float*)d_in[17];
    const float* h_u_b        = (const float*)d_in[18];
    const float* h_i_w        = (const float*)d_in[19];
    const float* h_i_b        = (const float*)d_in[20];
    const float* fc_pre_w     = (const float*)d_in[21];
    const float* fc_pre_b     = (const float*)d_in[22];

    // workspace layout
    unsigned short* bhi  = (unsigned short*)d_ws;      // 32768
    unsigned short* fuhi = bhi + 32768;                // 8192
    unsigned short* fihi = fuhi + 8192;                // 8192
    float* colsum = (float*)(fihi + 8192);             // 64
    float* u_vec  = colsum + 64;                       // NB*ND
    float* i_vec  = u_vec + NB * ND;                   // NB*ND

    prep_kernel<<<192, 256, 0, stream>>>(topic_w, fc_u_w, fc_ru_w, fc_i_w, fc_ri_w,
                                         bhi, fuhi, fihi);
    colsum_kernel<<<1, 256, 0, stream>>>(topic_w, colsum);

    branch_kernel<<<(2 * NB) / NE, 256, 0, stream>>>(
        user, item, user_r_topic, item_r_topic,
        user_embed_w, item_embed_w, user_att_w, item_att_w,
        bhi, fuhi, fihi,
        fc_u_b, fc_ru_b, fc_i_b, fc_ri_b,
        h_u_w, h_u_b, h_i_w, h_i_b,
        colsum, u_vec, i_vec);

    final_kernel<<<NB, 64, 0, stream>>>(u_vec, i_vec, fc_pre_w, fc_pre_b,
                                        (float*)d_out);
}